// Round 4
// baseline (138.083 us; speedup 1.0000x reference)
//
#include <hip/hip_runtime.h>

#define BATCH   8
#define SHAPE_N 8192
#define SKEL_M  2048

// ws layout (floats):
//   [0, 512):            dir1 per-block partial sums (plain stores)
//   [512, 66048):        dir2 partial mins, [quarter q<4][batch b<8][apt 2048]
//   [66048]:             arrival counter (int), zeroed by cd_prep
//   [66176, 197248):     skel converted  (8 batches * 4096 uint4 = 512 KB)
//   [197248, 721536):    shape converted (8 batches * 16384 uint4 = 2 MB)
// Every slot read is written earlier in the same iteration (stream order or
// fence+counter order), so no ws init dependence (re-poison-safe).
#define WS2_OFF 512
#define CNT_OFF 66048
#define SKC_OFF 66176
#define SHC_OFF (66176 + 131072)

// MFMA frag types (gfx950: 32x32x16 bf16 — A/B = 8 bf16 (4 VGPRs), C/D = 16 f32)
typedef short bf16x8 __attribute__((ext_vector_type(8)));
typedef float f32x16 __attribute__((ext_vector_type(16)));
union FragU { bf16x8 v; uint4 u4; };

// round-to-nearest-even f32 -> bf16 (result in low 16 bits)
__device__ __forceinline__ unsigned int f2bf(float a) {
    unsigned int u = __float_as_uint(a);
    return (u + 0x7FFFu + ((u >> 16) & 1u)) >> 16;
}
__device__ __forceinline__ float bf2f(unsigned int h) {
    return __uint_as_float(h << 16);
}
__device__ __forceinline__ unsigned int pack2(unsigned int lo, unsigned int hi) {
    return lo | (hi << 16);
}
// v ~= hi + lo (two bf16), residual ~2^-16 relative
__device__ __forceinline__ void bfsplit(float v, unsigned int& h, unsigned int& l) {
    h = f2bf(v);
    l = f2bf(v - bf2f(h));
}

// Converted A-operand (streamed side) for one b-point, hi/lo scheme identical
// to the verified R1/R3 kernels:
//   k=0..2 c_hi  k=3 rb_hi  k=4..6 c_hi  k=7 rb_lo | k=8..10 c_lo  k=11..15 0
__device__ __forceinline__ void conv_point(float bx, float by, float bz,
                                           uint4& hi, uint4& lo) {
    const float cx = -2.f * bx, cy = -2.f * by, cz = -2.f * bz;
    const float rb = bx * bx + by * by + bz * bz;
    unsigned int chx, clx, chy, cly, chz, clz, rbh, rbl;
    bfsplit(cx, chx, clx); bfsplit(cy, chy, cly); bfsplit(cz, chz, clz);
    bfsplit(rb, rbh, rbl);
    hi = make_uint4(pack2(chx, chy), pack2(chz, rbh),
                    pack2(chx, chy), pack2(chz, rbl));
    lo = make_uint4(pack2(clx, cly), pack2(clz, 0u), 0u, 0u);
}

// ---------------------------------------------------------------------------
// cd_prep: convert every b-side point ONCE into fragment order (group g of
// 32 points: 32 hi-uint4 then 32 lo-uint4 = 1 KB/group), so cd_main's waves
// can load A-fragments straight from global with coalesced dwordx4.
// Also zeroes cd_main's arrival counter (stream-ordered before cd_main).
// ---------------------------------------------------------------------------
__global__ __launch_bounds__(256) void cd_prep(
    const float* __restrict__ shape, const float* __restrict__ skel,
    float* __restrict__ ws)
{
    if (blockIdx.x == 0 && threadIdx.x == 0)
        ((int*)ws)[CNT_OFF] = 0;

    const int p = blockIdx.x * 256 + threadIdx.x;      // 0 .. 81919
    const float* q;
    uint4* dst;
    int idx;
    if (p < BATCH * SKEL_M) {                          // skel: stride 3
        const int b = p >> 11; idx = p & (SKEL_M - 1);
        q = skel + (size_t)p * 3;
        dst = (uint4*)(ws + SKC_OFF) + (size_t)b * 4096;
    } else {                                           // shape: stride 6
        const int s = p - BATCH * SKEL_M;
        const int b = s >> 13; idx = s & (SHAPE_N - 1);
        q = shape + (size_t)s * 6;
        dst = (uint4*)(ws + SHC_OFF) + (size_t)b * 16384;
    }
    uint4 hi, lo;
    conv_point(q[0], q[1], q[2], hi, lo);
    const int g = idx >> 5, r = idx & 31;
    dst[g * 64 + r]      = hi;
    dst[g * 64 + 32 + r] = lo;
}

// ---------------------------------------------------------------------------
// Scan 2048 converted b-points against the block's 128 resident a-points.
// NO LDS, NO BARRIERS: each wave loads its quarter's A-fragments directly
// from global (L2-hot, 1 KB coalesced per wave-load, 16 loads total) into
// VGPRs; one fragment feeds 4 MFMAs. 8-deep unroll gives 8 loads in flight,
// fully hiding ~200-300 cyc L2 latency under the ~800 cyc of compute.
// ---------------------------------------------------------------------------
template <int SA>
__device__ __forceinline__ void cd_scan2(
    const float* __restrict__ Araw,   // 128 a-points, stride SA
    const uint4* __restrict__ Bconv,  // 4096 uint4 = 2048 converted b-points
    float* rmin, float* ra)           // [4] outputs per lane (a-group j)
{
    const int tid = threadIdx.x;
    const int l = tid & 63, wv = tid >> 6;
    const unsigned int one = 0x3F80u;

    // resident B-operand frags: col n = l&31; lane-halves are k 0..7 / 8..15
    FragU bf[4];
#pragma unroll
    for (int j = 0; j < 4; ++j) {
        const float* p = Araw + (size_t)(j * 32 + (l & 31)) * SA;
        const float x = p[0], y = p[1], z = p[2];
        ra[j] = x * x + y * y + z * z;
        unsigned int hx, lx, hy, ly, hz, lz;
        bfsplit(x, hx, lx); bfsplit(y, hy, ly); bfsplit(z, hz, lz);
        if (l < 32)    // k=0..7: (a_hi, 1, a_lo, 1)
            bf[j].u4 = make_uint4(pack2(hx, hy), pack2(hz, one),
                                  pack2(lx, ly), pack2(lz, one));
        else           // k=8..15: (a_hi, 0, 0, 0)
            bf[j].u4 = make_uint4(pack2(hx, hy), pack2(hz, 0u), 0u, 0u);
        rmin[j] = 3.4e38f;
    }

    const f32x16 Z = {0,0,0,0,0,0,0,0,0,0,0,0,0,0,0,0};
    // wave wv owns b-point groups [wv*16, wv*16+16): 16 KB contiguous
    const char* p0 = (const char*)Bconv + wv * 16384 +
                     (l >> 5) * 512 + (l & 31) * 16;

#pragma unroll 8
    for (int g = 0; g < 16; ++g) {
        FragU af;
        af.u4 = *(const uint4*)(p0 + g * 1024);
#pragma unroll
        for (int j = 0; j < 4; ++j) {
            f32x16 D = __builtin_amdgcn_mfma_f32_32x32x16_bf16(
                af.v, bf[j].v, Z, 0, 0, 0);
            // 8x v_min3 tree + 1 min3 into the running min
            const float t0 = fminf(fminf(D[0],  D[1]),  D[2]);
            const float t1 = fminf(fminf(D[3],  D[4]),  D[5]);
            const float t2 = fminf(fminf(D[6],  D[7]),  D[8]);
            const float t3 = fminf(fminf(D[9],  D[10]), D[11]);
            const float t4 = fminf(fminf(D[12], D[13]), D[14]);
            const float u0 = fminf(fminf(t0, t1), t2);
            const float u1 = fminf(fminf(t3, t4), D[15]);
            rmin[j] = fminf(rmin[j], fminf(u0, u1));
        }
    }
    // lane l and l^32 cover complementary rows (b-points) of the same col
#pragma unroll
    for (int j = 0; j < 4; ++j)
        rmin[j] = fminf(rmin[j], __shfl_xor(rmin[j], 32, 64));
}

// ---------------------------------------------------------------------------
// 1024 equal blocks (64 MFMA/wave), no main-loop LDS/barriers:
//   [0,512):    dir1 — a = shape (128 pts), b = full skel (converted).
//               Cross-wave min -> sqrt+block-sum -> ws[bid].
//   [512,1024): dir2 — a = skel (128 pts), b = one converted shape quarter.
//               Cross-wave min -> plain stores into this quarter's ws slice.
// Tail: per-thread threadfence (release stores) + arrival counter; the
// last-arriving block min-folds the 4 dir2 quarters (64 float4 loads/thread,
// fixed order), adds the 512 dir1 partials, writes out[0]. Deterministic.
// Pattern (fence + device-scope atomicAdd + fence) verified passing in R2.
// ---------------------------------------------------------------------------
__global__ __launch_bounds__(256, 4) void cd_main(
    const float* __restrict__ shape, const float* __restrict__ skel,
    float* __restrict__ ws, float* __restrict__ out)
{
    __shared__ float smin[4][128];
    __shared__ float sra[128];
    __shared__ float s_wsum[4];
    __shared__ int s_last;
    const int tid = threadIdx.x;
    const int l = tid & 63, wv = tid >> 6;
    const int bid = blockIdx.x;
    float rmin[4], ra[4];

    if (bid < 512) {                   // dir1
        const int b = bid >> 6, sub = bid & 63;
        cd_scan2<6>(shape + ((size_t)b * SHAPE_N + sub * 128) * 6,
                    (const uint4*)(ws + SKC_OFF) + (size_t)b * 4096,
                    rmin, ra);
    } else {                           // dir2
        const int j = bid - 512;
        const int b = j >> 6, rem = j & 63;
        const int asub = rem >> 2, bs = rem & 3;
        cd_scan2<3>(skel + ((size_t)b * SKEL_M + asub * 128) * 3,
                    (const uint4*)(ws + SHC_OFF) + (size_t)b * 16384 + bs * 4096,
                    rmin, ra);
    }

    // combine the 4 waves' partial mins (each saw 1/4 of the b-points)
    if (l < 32) {
#pragma unroll
        for (int j = 0; j < 4; ++j) smin[wv][j * 32 + l] = rmin[j];
        if (wv == 0) {
#pragma unroll
            for (int j = 0; j < 4; ++j) sra[j * 32 + l] = ra[j];
        }
    }
    __syncthreads();

    if (bid < 512) {
        float d = 0.f;
        if (tid < 128) {
            const float m = fminf(fminf(smin[0][tid], smin[1][tid]),
                                  fminf(smin[2][tid], smin[3][tid]));
            d = sqrtf(fmaxf(sra[tid] + m, 0.f));
        }
        for (int o = 32; o; o >>= 1) d += __shfl_down(d, o, 64);
        if (l == 0 && wv < 2) s_wsum[wv] = d;
        __syncthreads();
        if (tid == 0) ws[bid] = s_wsum[0] + s_wsum[1];
    } else {
        if (tid < 128) {
            const int j = bid - 512;
            const int b = j >> 6, rem = j & 63;
            const int asub = rem >> 2, bs = rem & 3;
            const float m = fminf(fminf(smin[0][tid], smin[1][tid]),
                                  fminf(smin[2][tid], smin[3][tid]));
            ws[WS2_OFF + bs * (BATCH * SKEL_M) + b * SKEL_M +
               asub * 128 + tid] = sra[tid] + m;
        }
    }

    // --- arrival + last-block deterministic final reduce ---
    __threadfence();                                   // release this block's stores
    __syncthreads();
    if (tid == 0) {
        const int old = atomicAdd((int*)ws + CNT_OFF, 1);
        s_last = (old == 1023);
    }
    __syncthreads();
    if (s_last) {
        __threadfence();                               // acquire all partials
        float s = 0.f;
        const float4* w4 = (const float4*)(ws + WS2_OFF);
#pragma unroll
        for (int r = 0; r < 16; ++r) {
            const int i4 = r * 256 + tid;              // float4 idx within 4096
            float4 v0 = w4[i4];
            const float4 v1 = w4[4096 + i4];
            const float4 v2 = w4[8192 + i4];
            const float4 v3 = w4[12288 + i4];
            v0.x = fminf(fminf(v0.x, v1.x), fminf(v2.x, v3.x));
            v0.y = fminf(fminf(v0.y, v1.y), fminf(v2.y, v3.y));
            v0.z = fminf(fminf(v0.z, v1.z), fminf(v2.z, v3.z));
            v0.w = fminf(fminf(v0.w, v1.w), fminf(v2.w, v3.w));
            s += sqrtf(fmaxf(v0.x, 0.f)) + sqrtf(fmaxf(v0.y, 0.f)) +
                 sqrtf(fmaxf(v0.z, 0.f)) + sqrtf(fmaxf(v0.w, 0.f));
        }
        s += ws[tid] + ws[tid + 256];                  // dir1 partials (512)
        for (int o = 32; o; o >>= 1) s += __shfl_down(s, o, 64);
        if (l == 0) s_wsum[wv] = s;
        __syncthreads();
        if (tid == 0)
            out[0] = (s_wsum[0] + s_wsum[1] + s_wsum[2] + s_wsum[3]) * 1e-4f;
    }
}

extern "C" void kernel_launch(void* const* d_in, const int* in_sizes, int n_in,
                              void* d_out, int out_size, void* d_ws, size_t ws_size,
                              hipStream_t stream) {
    const float* shape = (const float*)d_in[0];   // (8, 8192, 6) — use first 3
    const float* skel  = (const float*)d_in[1];   // (8, 2048, 3)
    float* out         = (float*)d_out;           // scalar
    float* ws          = (float*)d_ws;            // >= 721536 floats = 2.82 MB

    cd_prep<<<320, 256, 0, stream>>>(shape, skel, ws);
    cd_main<<<1024, 256, 0, stream>>>(shape, skel, ws, out);
}

// Round 5
// 72.609 us; speedup vs baseline: 1.9017x; 1.9017x over previous
//
#include <hip/hip_runtime.h>

#define BATCH   8
#define SHAPE_N 8192
#define SKEL_M  2048

// ws layout (floats):
//   [0, 512):            dir1 per-block partial sums (plain stores)
//   [512, 66048):        dir2 partial mins, [quarter q<4][batch b<8][apt 2048]
//   [66048]:             reduce arrival counter (int), zeroed by cd_prep
//   [66056, 66120):      cd_reduce per-block partials (64 floats)
//   [66176, 197248):     skel converted  (8 batches * 4096 uint4 = 512 KB)
//   [197248, 721536):    shape converted (8 batches * 16384 uint4 = 2 MB)
// Every slot read is written earlier in the same iteration (stream order or
// fence+counter order), so no ws init dependence (re-poison-safe).
#define WS2_OFF 512
#define CNT_OFF 66048
#define RED_OFF 66056
#define SKC_OFF 66176
#define SHC_OFF (66176 + 131072)

// MFMA frag types (gfx950: 32x32x16 bf16 — A/B = 8 bf16 (4 VGPRs), C/D = 16 f32)
typedef short bf16x8 __attribute__((ext_vector_type(8)));
typedef float f32x16 __attribute__((ext_vector_type(16)));
union FragU { bf16x8 v; uint4 u4; };

// round-to-nearest-even f32 -> bf16 (result in low 16 bits)
__device__ __forceinline__ unsigned int f2bf(float a) {
    unsigned int u = __float_as_uint(a);
    return (u + 0x7FFFu + ((u >> 16) & 1u)) >> 16;
}
__device__ __forceinline__ float bf2f(unsigned int h) {
    return __uint_as_float(h << 16);
}
__device__ __forceinline__ unsigned int pack2(unsigned int lo, unsigned int hi) {
    return lo | (hi << 16);
}
// v ~= hi + lo (two bf16), residual ~2^-16 relative
__device__ __forceinline__ void bfsplit(float v, unsigned int& h, unsigned int& l) {
    h = f2bf(v);
    l = f2bf(v - bf2f(h));
}

// Converted A-operand (streamed side) for one b-point, hi/lo scheme identical
// to the verified R1/R3 kernels:
//   k=0..2 c_hi  k=3 rb_hi  k=4..6 c_hi  k=7 rb_lo | k=8..10 c_lo  k=11..15 0
__device__ __forceinline__ void conv_point(float bx, float by, float bz,
                                           uint4& hi, uint4& lo) {
    const float cx = -2.f * bx, cy = -2.f * by, cz = -2.f * bz;
    const float rb = bx * bx + by * by + bz * bz;
    unsigned int chx, clx, chy, cly, chz, clz, rbh, rbl;
    bfsplit(cx, chx, clx); bfsplit(cy, chy, cly); bfsplit(cz, chz, clz);
    bfsplit(rb, rbh, rbl);
    hi = make_uint4(pack2(chx, chy), pack2(chz, rbh),
                    pack2(chx, chy), pack2(chz, rbl));
    lo = make_uint4(pack2(clx, cly), pack2(clz, 0u), 0u, 0u);
}

// ---------------------------------------------------------------------------
// cd_prep: convert every b-side point ONCE into fragment order (group g of
// 32 points: 32 hi-uint4 then 32 lo-uint4 = 1 KB/group), so cd_main's waves
// can load A-fragments straight from global with coalesced dwordx4.
// Also zeroes cd_reduce's arrival counter (stream-ordered before cd_reduce).
// ---------------------------------------------------------------------------
__global__ __launch_bounds__(256) void cd_prep(
    const float* __restrict__ shape, const float* __restrict__ skel,
    float* __restrict__ ws)
{
    if (blockIdx.x == 0 && threadIdx.x == 0)
        ((int*)ws)[CNT_OFF] = 0;

    const int p = blockIdx.x * 256 + threadIdx.x;      // 0 .. 81919
    const float* q;
    uint4* dst;
    int idx;
    if (p < BATCH * SKEL_M) {                          // skel: stride 3
        const int b = p >> 11; idx = p & (SKEL_M - 1);
        q = skel + (size_t)p * 3;
        dst = (uint4*)(ws + SKC_OFF) + (size_t)b * 4096;
    } else {                                           // shape: stride 6
        const int s = p - BATCH * SKEL_M;
        const int b = s >> 13; idx = s & (SHAPE_N - 1);
        q = shape + (size_t)s * 6;
        dst = (uint4*)(ws + SHC_OFF) + (size_t)b * 16384;
    }
    uint4 hi, lo;
    conv_point(q[0], q[1], q[2], hi, lo);
    const int g = idx >> 5, r = idx & 31;
    dst[g * 64 + r]      = hi;
    dst[g * 64 + 32 + r] = lo;
}

// one MFMA step: fragment af vs all 4 resident a-group frags, fold into rmin
__device__ __forceinline__ void step_min(const FragU& af, const FragU* bf,
                                         float* rmin)
{
    const f32x16 Z = {0,0,0,0,0,0,0,0,0,0,0,0,0,0,0,0};
#pragma unroll
    for (int j = 0; j < 4; ++j) {
        f32x16 D = __builtin_amdgcn_mfma_f32_32x32x16_bf16(
            af.v, bf[j].v, Z, 0, 0, 0);
        // 8x v_min3 tree into the running min
        const float t0 = fminf(fminf(D[0],  D[1]),  D[2]);
        const float t1 = fminf(fminf(D[3],  D[4]),  D[5]);
        const float t2 = fminf(fminf(D[6],  D[7]),  D[8]);
        const float t3 = fminf(fminf(D[9],  D[10]), D[11]);
        const float t4 = fminf(fminf(D[12], D[13]), D[14]);
        const float u0 = fminf(fminf(t0, t1), t2);
        const float u1 = fminf(fminf(t3, t4), D[15]);
        rmin[j] = fminf(rmin[j], fminf(u0, u1));
    }
}

// ---------------------------------------------------------------------------
// Scan 2048 converted b-points against the block's 128 resident a-points.
// NO LDS, NO BARRIERS. Explicit 8-deep software pipeline: preload 8 fragments
// into named VGPR slots (static indices only), then {compute slot g, refill
// slot g with fragment g+8}. Loads are issued 8 ahead of their consuming
// MFMA, so waits are counted vmcnt(~8), not load->use stalls. In flight:
// 8 x 1 KB/wave x 16 waves/CU = 128 KB/CU — covers IF$/L2 latency under
// full-chip contention. (R4's flat unroll gave VGPR=36: compiler sank each
// load to its use -> serial latency. This structure forces the pipeline.)
// ---------------------------------------------------------------------------
template <int SA>
__device__ __forceinline__ void cd_scan2(
    const float* __restrict__ Araw,   // 128 a-points, stride SA
    const uint4* __restrict__ Bconv,  // 4096 uint4 = 2048 converted b-points
    float* rmin, float* ra)           // [4] outputs per lane (a-group j)
{
    const int tid = threadIdx.x;
    const int l = tid & 63, wv = tid >> 6;
    const unsigned int one = 0x3F80u;

    // resident B-operand frags: col n = l&31; lane-halves are k 0..7 / 8..15
    FragU bf[4];
#pragma unroll
    for (int j = 0; j < 4; ++j) {
        const float* p = Araw + (size_t)(j * 32 + (l & 31)) * SA;
        const float x = p[0], y = p[1], z = p[2];
        ra[j] = x * x + y * y + z * z;
        unsigned int hx, lx, hy, ly, hz, lz;
        bfsplit(x, hx, lx); bfsplit(y, hy, ly); bfsplit(z, hz, lz);
        if (l < 32)    // k=0..7: (a_hi, 1, a_lo, 1)
            bf[j].u4 = make_uint4(pack2(hx, hy), pack2(hz, one),
                                  pack2(lx, ly), pack2(lz, one));
        else           // k=8..15: (a_hi, 0, 0, 0)
            bf[j].u4 = make_uint4(pack2(hx, hy), pack2(hz, 0u), 0u, 0u);
        rmin[j] = 3.4e38f;
    }

    // wave wv owns b-point groups [wv*16, wv*16+16): 16 KB contiguous
    const char* p0 = (const char*)Bconv + wv * 16384 +
                     (l >> 5) * 512 + (l & 31) * 16;

    FragU f[8];
#pragma unroll
    for (int g = 0; g < 8; ++g)                    // issue 8 loads back-to-back
        f[g].u4 = *(const uint4*)(p0 + g * 1024);
#pragma unroll
    for (int g = 0; g < 8; ++g) {                  // steady state: use g, load g+8
        const FragU cur = f[g];
        f[g].u4 = *(const uint4*)(p0 + (g + 8) * 1024);
        step_min(cur, bf, rmin);
    }
#pragma unroll
    for (int g = 0; g < 8; ++g)                    // drain
        step_min(f[g], bf, rmin);

    // lane l and l^32 cover complementary rows (b-points) of the same col
#pragma unroll
    for (int j = 0; j < 4; ++j)
        rmin[j] = fminf(rmin[j], __shfl_xor(rmin[j], 32, 64));
}

// ---------------------------------------------------------------------------
// 1024 equal blocks (64 MFMA/wave), no main-loop LDS/barriers:
//   [0,512):    dir1 — a = shape (128 pts), b = full skel (converted).
//               Cross-wave min -> sqrt+block-sum -> ws[bid].
//   [512,1024): dir2 — a = skel (128 pts), b = one converted shape quarter.
//               Cross-wave min -> plain stores into this quarter's ws slice.
// Plain stores only; visibility to cd_reduce via the dispatch boundary
// (same pattern as the passing R1/R3 kernels). No fences here.
// ---------------------------------------------------------------------------
__global__ __launch_bounds__(256, 4) void cd_main(
    const float* __restrict__ shape, const float* __restrict__ skel,
    float* __restrict__ ws)
{
    __shared__ float smin[4][128];
    __shared__ float sra[128];
    __shared__ float s_wsum[2];
    const int tid = threadIdx.x;
    const int l = tid & 63, wv = tid >> 6;
    const int bid = blockIdx.x;
    float rmin[4], ra[4];

    if (bid < 512) {                   // dir1
        const int b = bid >> 6, sub = bid & 63;
        cd_scan2<6>(shape + ((size_t)b * SHAPE_N + sub * 128) * 6,
                    (const uint4*)(ws + SKC_OFF) + (size_t)b * 4096,
                    rmin, ra);
    } else {                           // dir2
        const int j = bid - 512;
        const int b = j >> 6, rem = j & 63;
        const int asub = rem >> 2, bs = rem & 3;
        cd_scan2<3>(skel + ((size_t)b * SKEL_M + asub * 128) * 3,
                    (const uint4*)(ws + SHC_OFF) + (size_t)b * 16384 + bs * 4096,
                    rmin, ra);
    }

    // combine the 4 waves' partial mins (each saw 1/4 of the b-points)
    if (l < 32) {
#pragma unroll
        for (int j = 0; j < 4; ++j) smin[wv][j * 32 + l] = rmin[j];
        if (wv == 0) {
#pragma unroll
            for (int j = 0; j < 4; ++j) sra[j * 32 + l] = ra[j];
        }
    }
    __syncthreads();

    if (bid < 512) {
        float d = 0.f;
        if (tid < 128) {
            const float m = fminf(fminf(smin[0][tid], smin[1][tid]),
                                  fminf(smin[2][tid], smin[3][tid]));
            d = sqrtf(fmaxf(sra[tid] + m, 0.f));
        }
        for (int o = 32; o; o >>= 1) d += __shfl_down(d, o, 64);
        if (l == 0 && wv < 2) s_wsum[wv] = d;
        __syncthreads();
        if (tid == 0) ws[bid] = s_wsum[0] + s_wsum[1];
    } else {
        if (tid < 128) {
            const int j = bid - 512;
            const int b = j >> 6, rem = j & 63;
            const int asub = rem >> 2, bs = rem & 3;
            const float m = fminf(fminf(smin[0][tid], smin[1][tid]),
                                  fminf(smin[2][tid], smin[3][tid]));
            ws[WS2_OFF + bs * (BATCH * SKEL_M) + b * SKEL_M +
               asub * 128 + tid] = sra[tid] + m;
        }
    }
}

// ---------------------------------------------------------------------------
// Parallel reduce: 64 blocks x 256 threads. Each thread owns one dir2
// a-point, min-folds its 4 quarter partials (coalesced, L2-resident),
// clamp+sqrt, block-sums. Blocks 0/1 also add the 512 dir1 partials.
// Each block writes ONE partial; the last-arriving block (fence + atomic
// counter, zeroed by cd_prep) sums the 64 partials in fixed order -> out[0].
// Deterministic. (Verified passing in R3.)
// ---------------------------------------------------------------------------
__global__ __launch_bounds__(256) void cd_reduce(
    float* __restrict__ ws, float* __restrict__ out)
{
    __shared__ float s_wsum[4];
    __shared__ int s_last;
    const int t = threadIdx.x;
    const int bid = blockIdx.x;
    const int l = t & 63, wv = t >> 6;
    const int i = bid * 256 + t;                  // a-point 0..16383

    const float v0 = ws[WS2_OFF + i];
    const float v1 = ws[WS2_OFF + 16384 + i];
    const float v2 = ws[WS2_OFF + 32768 + i];
    const float v3 = ws[WS2_OFF + 49152 + i];
    float s = sqrtf(fmaxf(fminf(fminf(v0, v1), fminf(v2, v3)), 0.f));
    if (bid < 2) s += ws[bid * 256 + t];          // dir1 per-block partials

    for (int o = 32; o; o >>= 1) s += __shfl_down(s, o, 64);
    if (l == 0) s_wsum[wv] = s;
    __syncthreads();
    if (t == 0) {
        ws[RED_OFF + bid] = s_wsum[0] + s_wsum[1] + s_wsum[2] + s_wsum[3];
        __threadfence();                          // release partial
        const int old = atomicAdd((int*)ws + CNT_OFF, 1);
        s_last = (old == 63);
    }
    __syncthreads();
    if (s_last && wv == 0) {
        __threadfence();                          // acquire all partials
        float f = ws[RED_OFF + l];                // 64 partials, fixed order
        for (int o = 32; o; o >>= 1) f += __shfl_down(f, o, 64);
        if (l == 0) out[0] = f * 1e-4f;
    }
}

extern "C" void kernel_launch(void* const* d_in, const int* in_sizes, int n_in,
                              void* d_out, int out_size, void* d_ws, size_t ws_size,
                              hipStream_t stream) {
    const float* shape = (const float*)d_in[0];   // (8, 8192, 6) — use first 3
    const float* skel  = (const float*)d_in[1];   // (8, 2048, 3)
    float* out         = (float*)d_out;           // scalar
    float* ws          = (float*)d_ws;            // >= 721536 floats = 2.82 MB

    cd_prep<<<320, 256, 0, stream>>>(shape, skel, ws);
    cd_main<<<1024, 256, 0, stream>>>(shape, skel, ws);
    cd_reduce<<<64, 256, 0, stream>>>(ws, out);
}